// Round 1
// baseline (150.816 us; speedup 1.0000x reference)
//
#include <hip/hip_runtime.h>

#define IN_F 4096
#define OUT_F 11008
#define NCLUST 16
#define TOPK 1024

// ---------------------------------------------------------------------------
// Kernel A: one block, 256 threads.
//  - softmax(|x|) -> activation
//  - argmin_cl ||center[cl] - activation||^2
//  - exact top-1024 selection of center[ci] via 4-pass radix select
//  - write masked x vector xm[4096] to workspace
// ---------------------------------------------------------------------------
__global__ __launch_bounds__(256) void select_mask_kernel(
    const float* __restrict__ x,
    const float* __restrict__ centers,
    float* __restrict__ xm)
{
    const int tid  = threadIdx.x;
    const int lane = tid & 63;
    const int wid  = tid >> 6;

    __shared__ float sx[IN_F];       // x values
    __shared__ float sact[IN_F];     // activation, later: chosen center values
    __shared__ float sred[256];
    __shared__ float sd2[NCLUST];
    __shared__ unsigned int shist[256];
    __shared__ unsigned int sscan[256];
    __shared__ unsigned int sprefix;
    __shared__ unsigned int sKrem;
    __shared__ unsigned int sG;
    __shared__ int sci;

    // ---- load x ----
    for (int i = tid; i < IN_F; i += 256) sx[i] = x[i];
    __syncthreads();

    // ---- max |x| ----
    float lm = 0.0f;
    for (int i = tid; i < IN_F; i += 256) lm = fmaxf(lm, fabsf(sx[i]));
    sred[tid] = lm;
    __syncthreads();
    for (int s = 128; s > 0; s >>= 1) {
        if (tid < s) sred[tid] = fmaxf(sred[tid], sred[tid + s]);
        __syncthreads();
    }
    const float mx = sred[0];
    __syncthreads();

    // ---- exp & sum ----
    float ls = 0.0f;
    for (int i = tid; i < IN_F; i += 256) {
        float e = expf(fabsf(sx[i]) - mx);
        sact[i] = e;
        ls += e;
    }
    sred[tid] = ls;
    __syncthreads();
    for (int s = 128; s > 0; s >>= 1) {
        if (tid < s) sred[tid] += sred[tid + s];
        __syncthreads();
    }
    const float inv = 1.0f / sred[0];
    __syncthreads();
    for (int i = tid; i < IN_F; i += 256) sact[i] *= inv;
    __syncthreads();

    // ---- distances to 16 centers (4 clusters per wave, wave-local reduce) ----
    for (int cl = wid; cl < NCLUST; cl += 4) {
        const float* c = centers + (size_t)cl * IN_F;
        float d = 0.0f;
        for (int i = lane; i < IN_F; i += 64) {
            float t = c[i] - sact[i];
            d += t * t;
        }
        for (int off = 32; off > 0; off >>= 1) d += __shfl_down(d, off, 64);
        if (lane == 0) sd2[cl] = d;
    }
    __syncthreads();
    if (tid == 0) {
        int b = 0; float bv = sd2[0];
        for (int c2 = 1; c2 < NCLUST; ++c2) {
            if (sd2[c2] < bv) { bv = sd2[c2]; b = c2; }
        }
        sci = b;
        sprefix = 0u;
        sKrem = TOPK;
        sG = 0u;
    }
    __syncthreads();

    // ---- load chosen center into sact (reuse) ----
    {
        const float* cc = centers + (size_t)sci * IN_F;
        for (int i = tid; i < IN_F; i += 256) sact[i] = cc[i];
    }
    __syncthreads();

    // cache this thread's contiguous 16 values in registers (positive floats:
    // unsigned bit compare == float compare)
    unsigned int cv[16];
    {
        const float4* p = reinterpret_cast<const float4*>(&sact[tid * 16]);
        #pragma unroll
        for (int q = 0; q < 4; ++q) {
            float4 v = p[q];
            cv[q * 4 + 0] = __float_as_uint(v.x);
            cv[q * 4 + 1] = __float_as_uint(v.y);
            cv[q * 4 + 2] = __float_as_uint(v.z);
            cv[q * 4 + 3] = __float_as_uint(v.w);
        }
    }

    // ---- 4-pass radix select for the 1024th-largest value ----
    for (int pass = 0; pass < 4; ++pass) {
        const int shift = 24 - 8 * pass;
        shist[tid] = 0u;
        __syncthreads();
        const unsigned int pfx = sprefix;
        #pragma unroll
        for (int j = 0; j < 16; ++j) {
            unsigned int u = cv[j];
            bool cand = (pass == 0) || ((u >> (shift + 8)) == pfx);
            if (cand) atomicAdd(&shist[(u >> shift) & 0xFFu], 1u);
        }
        __syncthreads();
        if (tid == 0) {
            unsigned int krem = sKrem;
            unsigned int cum = 0u;
            int b = 255;
            for (; b >= 0; --b) {
                unsigned int c = shist[b];
                if (cum + c >= krem) break;
                cum += c;
            }
            sKrem = krem - cum;
            sprefix = (sprefix << 8) | (unsigned int)b;
        }
        __syncthreads();
    }
    const unsigned int T = sprefix;  // bit pattern of the 1024th-largest value

    // ---- count strictly-greater (G) and per-thread equal counts ----
    unsigned int gt = 0u, eq = 0u;
    #pragma unroll
    for (int j = 0; j < 16; ++j) {
        gt += (cv[j] > T) ? 1u : 0u;
        eq += (cv[j] == T) ? 1u : 0u;
    }
    shist[tid] = eq;
    __syncthreads();
    atomicAdd(&sG, gt);
    __syncthreads();
    if (tid == 0) {
        unsigned int run = 0u;
        for (int t2 = 0; t2 < 256; ++t2) {
            sscan[t2] = run;
            run += shist[t2];
        }
    }
    __syncthreads();

    // ---- emit masked x (ties: first (TOPK - G) equal values in index order,
    //      matching jax.lax.top_k stability) ----
    const unsigned int needEq = TOPK - sG;
    unsigned int base = sscan[tid];
    unsigned int r = 0u;
    #pragma unroll
    for (int j = 0; j < 16; ++j) {
        int i = tid * 16 + j;
        unsigned int u = cv[j];
        bool sel = (u > T) || ((u == T) && (base + r < needEq));
        if (u == T) r++;
        xm[i] = sel ? sx[i] : 0.0f;
    }
}

// ---------------------------------------------------------------------------
// Kernel B: dense masked matvec  out[o] = W[o,:] . xm + bias[o]
// One row per wave, 2 rows per wave total (1376 blocks * 4 waves * 2 rows).
// ---------------------------------------------------------------------------
__global__ __launch_bounds__(256) void matvec_kernel(
    const float* __restrict__ W,
    const float* __restrict__ xm,
    const float* __restrict__ bias,
    float* __restrict__ out)
{
    __shared__ float sxm[IN_F];
    const int tid = threadIdx.x;
    // stage xm in LDS (float4, coalesced)
    for (int i = tid * 4; i < IN_F; i += 256 * 4) {
        *reinterpret_cast<float4*>(&sxm[i]) =
            *reinterpret_cast<const float4*>(&xm[i]);
    }
    __syncthreads();

    const int lane = tid & 63;
    const int wid  = tid >> 6;
    const int nwaves = gridDim.x * 4;

    for (int row = blockIdx.x * 4 + wid; row < OUT_F; row += nwaves) {
        const float4* wr = reinterpret_cast<const float4*>(W + (size_t)row * IN_F);
        float acc = 0.0f;
        #pragma unroll
        for (int j = 0; j < IN_F / 4 / 64; ++j) {     // 16 iterations
            float4 w4 = wr[j * 64 + lane];
            float4 x4 = *reinterpret_cast<const float4*>(&sxm[(j * 64 + lane) * 4]);
            acc += w4.x * x4.x + w4.y * x4.y + w4.z * x4.z + w4.w * x4.w;
        }
        for (int off = 32; off > 0; off >>= 1) acc += __shfl_down(acc, off, 64);
        if (lane == 0) out[row] = acc + bias[row];
    }
}

extern "C" void kernel_launch(void* const* d_in, const int* in_sizes, int n_in,
                              void* d_out, int out_size, void* d_ws, size_t ws_size,
                              hipStream_t stream) {
    const float* x       = (const float*)d_in[0];  // [1,1,4096]
    const float* weight  = (const float*)d_in[1];  // [11008,4096]
    const float* bias    = (const float*)d_in[2];  // [11008]
    const float* centers = (const float*)d_in[3];  // [16,4096]
    float* out = (float*)d_out;                    // [11008]
    float* xm  = (float*)d_ws;                     // 4096 floats scratch

    select_mask_kernel<<<1, 256, 0, stream>>>(x, centers, xm);
    matvec_kernel<<<1376, 256, 0, stream>>>(weight, xm, bias, out);
}

// Round 2
// 45.648 us; speedup vs baseline: 3.3039x; 3.3039x over previous
//
#include <hip/hip_runtime.h>

#define IN_F 4096
#define OUT_F 11008
#define NCLUST 16
#define TOPK 1024
#define NT 1024   // threads in select kernel (16 waves)
#define NW 16

// ---------------------------------------------------------------------------
// Kernel A: one block, 1024 threads (16 waves). Fully parallel:
//  softmax(|x|) -> argmin distance over 16 centers -> exact top-1024 radix
//  select (per-wave private histograms + shuffle suffix-scan) -> masked x.
// ---------------------------------------------------------------------------
__global__ __launch_bounds__(NT) void select_mask_kernel(
    const float* __restrict__ x,
    const float* __restrict__ centers,
    float* __restrict__ xm)
{
    const int tid  = threadIdx.x;
    const int lane = tid & 63;
    const int wid  = tid >> 6;

    __shared__ __align__(16) float sx[IN_F];    // raw x
    __shared__ __align__(16) float sact[IN_F];  // normalized activation
    __shared__ unsigned int hist[NW * 256];     // per-wave private histograms
    __shared__ float swred[NW];
    __shared__ float sd2[NCLUST];
    __shared__ unsigned int wtot4[4];
    __shared__ unsigned int weq[NW];
    __shared__ float smax, ssum;
    __shared__ unsigned int sprefix, sKrem, sG;
    __shared__ int sci;

    if (tid == 0) { sprefix = 0u; sKrem = TOPK; sG = 0u; }

    // ---- load x (one float4 per thread) + wave max of |x| ----
    float4 xv = reinterpret_cast<const float4*>(x)[tid];
    reinterpret_cast<float4*>(sx)[tid] = xv;
    {
        float m = fmaxf(fmaxf(fabsf(xv.x), fabsf(xv.y)),
                        fmaxf(fabsf(xv.z), fabsf(xv.w)));
        for (int off = 32; off > 0; off >>= 1) m = fmaxf(m, __shfl_down(m, off, 64));
        if (lane == 0) swred[wid] = m;
    }
    __syncthreads();
    if (wid == 0) {
        float m = (lane < NW) ? swred[lane] : -3.0e38f;
        for (int off = 8; off > 0; off >>= 1) m = fmaxf(m, __shfl_down(m, off, 64));
        if (lane == 0) smax = m;
    }
    __syncthreads();
    const float mx = smax;

    // ---- exp (in regs) + block sum ----
    float e0 = expf(fabsf(xv.x) - mx);
    float e1 = expf(fabsf(xv.y) - mx);
    float e2 = expf(fabsf(xv.z) - mx);
    float e3 = expf(fabsf(xv.w) - mx);
    {
        float s = e0 + e1 + e2 + e3;
        for (int off = 32; off > 0; off >>= 1) s += __shfl_down(s, off, 64);
        if (lane == 0) swred[wid] = s;   // safe: prior swred reads were before last barrier? 
    }
    __syncthreads();
    if (wid == 0) {
        float s = (lane < NW) ? swred[lane] : 0.0f;
        for (int off = 8; off > 0; off >>= 1) s += __shfl_down(s, off, 64);
        if (lane == 0) ssum = s;
    }
    __syncthreads();
    {
        const float inv = 1.0f / ssum;
        float4 a;
        a.x = e0 * inv; a.y = e1 * inv; a.z = e2 * inv; a.w = e3 * inv;
        reinterpret_cast<float4*>(sact)[tid] = a;
    }
    __syncthreads();

    // ---- distances: wave w handles cluster w ----
    {
        const float4* c4 = reinterpret_cast<const float4*>(centers + (size_t)wid * IN_F);
        const float4* a4 = reinterpret_cast<const float4*>(sact);
        float d = 0.0f;
        #pragma unroll
        for (int it = 0; it < IN_F / 4 / 64; ++it) {   // 16
            float4 c = c4[it * 64 + lane];
            float4 a = a4[it * 64 + lane];
            float t0 = c.x - a.x, t1 = c.y - a.y, t2 = c.z - a.z, t3 = c.w - a.w;
            d += t0 * t0 + t1 * t1 + t2 * t2 + t3 * t3;
        }
        for (int off = 32; off > 0; off >>= 1) d += __shfl_down(d, off, 64);
        if (lane == 0) sd2[wid] = d;
    }
    __syncthreads();

    // ---- argmin over 16 (first-min-index semantics) ----
    if (wid == 0) {
        float v = (lane < NCLUST) ? sd2[lane] : 3.0e38f;
        int   bi = lane;
        for (int off = 8; off > 0; off >>= 1) {
            float ov = __shfl_down(v, off, 64);
            int   oi = __shfl_down(bi, off, 64);
            if (ov < v) { v = ov; bi = oi; }   // strict <: ties keep smaller index
        }
        if (lane == 0) sci = bi;
    }
    __syncthreads();

    // ---- chosen center values (positive floats: uint cmp == float cmp) ----
    unsigned int cv[4];
    {
        float4 c = reinterpret_cast<const float4*>(centers + (size_t)sci * IN_F)[tid];
        cv[0] = __float_as_uint(c.x);
        cv[1] = __float_as_uint(c.y);
        cv[2] = __float_as_uint(c.z);
        cv[3] = __float_as_uint(c.w);
    }

    // ---- 4-pass radix select for 1024th-largest ----
    for (int pass = 0; pass < 4; ++pass) {
        const int shift = 24 - 8 * pass;
        for (int k = tid; k < NW * 256; k += NT) hist[k] = 0u;
        __syncthreads();
        const unsigned int pfx  = sprefix;
        const unsigned int krem = sKrem;
        unsigned int* hp = &hist[wid * 256];
        #pragma unroll
        for (int j = 0; j < 4; ++j) {
            unsigned int u = cv[j];
            bool cand = (pass == 0) || ((u >> (shift + 8)) == pfx);
            if (cand) atomicAdd(&hp[(u >> shift) & 255u], 1u);
        }
        __syncthreads();
        unsigned int h = 0, s = 0;
        if (tid < 256) {
            #pragma unroll
            for (int w = 0; w < NW; ++w) h += hist[w * 256 + tid];
            // suffix-inclusive scan within this 64-lane wave (bin order)
            s = h;
            for (int off = 1; off < 64; off <<= 1) {
                unsigned int v2 = __shfl_down(s, off, 64);
                if (lane + off < 64) s += v2;
            }
            if (lane == 0) wtot4[wid] = s;   // wave total (wid 0..3)
        }
        __syncthreads();
        if (tid < 256) {
            unsigned int add = 0;
            #pragma unroll
            for (int w = 0; w < 4; ++w) if (w > wid) add += wtot4[w];
            unsigned int incl = s + add;       // count of values in bins >= tid
            unsigned int excl = incl - h;      // count of values in bins >  tid
            if (excl < krem && krem <= incl) { // exactly one thread
                sprefix = (pfx << 8) | (unsigned int)tid;
                sKrem   = krem - excl;
            }
        }
        __syncthreads();
    }
    const unsigned int T = sprefix;  // bit pattern of 1024th-largest center value

    // ---- tie bookkeeping: G = #strictly-greater, stable eq-prefix ----
    unsigned int gt = 0, eq = 0;
    #pragma unroll
    for (int j = 0; j < 4; ++j) {
        gt += (cv[j] > T) ? 1u : 0u;
        eq += (cv[j] == T) ? 1u : 0u;
    }
    {
        unsigned int g = gt;
        for (int off = 32; off > 0; off >>= 1) g += __shfl_down(g, off, 64);
        if (lane == 0) atomicAdd(&sG, g);
    }
    unsigned int p = eq;  // inclusive prefix within wave
    for (int off = 1; off < 64; off <<= 1) {
        unsigned int v2 = __shfl_up(p, off, 64);
        if (lane >= off) p += v2;
    }
    if (lane == 63) weq[wid] = p;
    __syncthreads();
    unsigned int base = p - eq;
    #pragma unroll
    for (int w = 0; w < NW; ++w) if (w < wid) base += weq[w];
    const unsigned int needEq = TOPK - sG;

    // ---- emit masked x ----
    {
        unsigned int r = 0;
        float4 o;
        o.x = ((cv[0] > T) || ((cv[0] == T) && (base + r < needEq))) ? xv.x : 0.0f; r += (cv[0] == T);
        o.y = ((cv[1] > T) || ((cv[1] == T) && (base + r < needEq))) ? xv.y : 0.0f; r += (cv[1] == T);
        o.z = ((cv[2] > T) || ((cv[2] == T) && (base + r < needEq))) ? xv.z : 0.0f; r += (cv[2] == T);
        o.w = ((cv[3] > T) || ((cv[3] == T) && (base + r < needEq))) ? xv.w : 0.0f;
        reinterpret_cast<float4*>(xm)[tid] = o;
    }
}

// ---------------------------------------------------------------------------
// Kernel B: dense masked matvec  out[o] = W[o,:] . xm + bias[o]
// ---------------------------------------------------------------------------
__global__ __launch_bounds__(256) void matvec_kernel(
    const float* __restrict__ W,
    const float* __restrict__ xm,
    const float* __restrict__ bias,
    float* __restrict__ out)
{
    __shared__ __align__(16) float sxm[IN_F];
    const int tid = threadIdx.x;
    for (int i = tid * 4; i < IN_F; i += 256 * 4) {
        *reinterpret_cast<float4*>(&sxm[i]) =
            *reinterpret_cast<const float4*>(&xm[i]);
    }
    __syncthreads();

    const int lane = tid & 63;
    const int wid  = tid >> 6;
    const int nwaves = gridDim.x * 4;

    for (int row = blockIdx.x * 4 + wid; row < OUT_F; row += nwaves) {
        const float4* wr = reinterpret_cast<const float4*>(W + (size_t)row * IN_F);
        float acc = 0.0f;
        #pragma unroll
        for (int j = 0; j < IN_F / 4 / 64; ++j) {     // 16 iterations
            float4 w4 = wr[j * 64 + lane];
            float4 x4 = *reinterpret_cast<const float4*>(&sxm[(j * 64 + lane) * 4]);
            acc += w4.x * x4.x + w4.y * x4.y + w4.z * x4.z + w4.w * x4.w;
        }
        for (int off = 32; off > 0; off >>= 1) acc += __shfl_down(acc, off, 64);
        if (lane == 0) out[row] = acc + bias[row];
    }
}

extern "C" void kernel_launch(void* const* d_in, const int* in_sizes, int n_in,
                              void* d_out, int out_size, void* d_ws, size_t ws_size,
                              hipStream_t stream) {
    const float* x       = (const float*)d_in[0];  // [1,1,4096]
    const float* weight  = (const float*)d_in[1];  // [11008,4096]
    const float* bias    = (const float*)d_in[2];  // [11008]
    const float* centers = (const float*)d_in[3];  // [16,4096]
    float* out = (float*)d_out;                    // [11008]
    float* xm  = (float*)d_ws;                     // 4096 floats scratch

    select_mask_kernel<<<1, NT, 0, stream>>>(x, centers, xm);
    matvec_kernel<<<1376, 256, 0, stream>>>(weight, xm, bias, out);
}

// Round 3
// 45.403 us; speedup vs baseline: 3.3218x; 1.0054x over previous
//
#include <hip/hip_runtime.h>

#define IN_F 4096
#define OUT_F 11008
#define NCLUST 16
#define TOPK 1024
#define NT 1024   // threads in select kernel (16 waves)
#define NW 16

// ---------------------------------------------------------------------------
// Kernel A: one block, 1024 threads (16 waves).
//  - prefetch wave's cluster center into 64 VGPRs at entry (hides HBM latency
//    under the softmax reductions)
//  - softmax denominator trick: argmin ||c - e/S||^2 == argmin [Sum c^2 - (2/S) c.e]
//    so distances use unnormalized e (one less pass/barrier)
//  - exact top-1024 radix select (per-wave private histograms + shuffle scans)
//  - write masked x to xm
// ---------------------------------------------------------------------------
__global__ __launch_bounds__(NT, 4) void select_mask_kernel(
    const float* __restrict__ x,
    const float* __restrict__ centers,
    float* __restrict__ xm)
{
    const int tid  = threadIdx.x;
    const int lane = tid & 63;
    const int wid  = tid >> 6;

    __shared__ __align__(16) float sact[IN_F];  // e values, later chosen center
    __shared__ unsigned int hist[NW * 256];     // per-wave private histograms
    __shared__ float swred[NW];
    __shared__ float sdot[NCLUST];
    __shared__ float scsq[NCLUST];
    __shared__ unsigned int wtot4[4];
    __shared__ unsigned int weq[NW];
    __shared__ float smax;
    __shared__ unsigned int sprefix, sKrem, sG;
    __shared__ int sci;

    if (tid == 0) { sprefix = 0u; sKrem = TOPK; sG = 0u; }

    // ---- issue loads early: x (1 float4/thread) + this wave's cluster ----
    float4 xv = reinterpret_cast<const float4*>(x)[tid];
    float4 cpre[16];
    {
        const float4* c4 = reinterpret_cast<const float4*>(centers + (size_t)wid * IN_F);
        #pragma unroll
        for (int it = 0; it < 16; ++it) cpre[it] = c4[it * 64 + lane];
    }

    // ---- block max of |x| ----
    {
        float m = fmaxf(fmaxf(fabsf(xv.x), fabsf(xv.y)),
                        fmaxf(fabsf(xv.z), fabsf(xv.w)));
        for (int off = 32; off > 0; off >>= 1) m = fmaxf(m, __shfl_down(m, off, 64));
        if (lane == 0) swred[wid] = m;
    }
    __syncthreads();
    if (wid == 0) {
        float m = (lane < NW) ? swred[lane] : -3.0e38f;
        for (int off = 8; off > 0; off >>= 1) m = fmaxf(m, __shfl_down(m, off, 64));
        if (lane == 0) smax = m;
    }
    __syncthreads();
    const float mx = smax;

    // ---- e = exp(|x|-mx): store to LDS + per-wave partial sums ----
    float e0 = expf(fabsf(xv.x) - mx);
    float e1 = expf(fabsf(xv.y) - mx);
    float e2 = expf(fabsf(xv.z) - mx);
    float e3 = expf(fabsf(xv.w) - mx);
    {
        float4 ev; ev.x = e0; ev.y = e1; ev.z = e2; ev.w = e3;
        reinterpret_cast<float4*>(sact)[tid] = ev;
        float s = e0 + e1 + e2 + e3;
        for (int off = 32; off > 0; off >>= 1) s += __shfl_down(s, off, 64);
        if (lane == 0) swred[wid] = s;   // per-wave e-sums (combined later)
    }
    __syncthreads();

    // ---- per-cluster dot(c,e) and sum(c^2) from prefetched regs ----
    {
        const float4* a4 = reinterpret_cast<const float4*>(sact);
        float dt = 0.0f, cq = 0.0f;
        #pragma unroll
        for (int it = 0; it < 16; ++it) {
            float4 c = cpre[it];
            float4 a = a4[it * 64 + lane];
            dt += c.x * a.x + c.y * a.y + c.z * a.z + c.w * a.w;
            cq += c.x * c.x + c.y * c.y + c.z * c.z + c.w * c.w;
        }
        for (int off = 32; off > 0; off >>= 1) {
            dt += __shfl_down(dt, off, 64);
            cq += __shfl_down(cq, off, 64);
        }
        if (lane == 0) { sdot[wid] = dt; scsq[wid] = cq; }
    }
    __syncthreads();

    // ---- argmin_cl [ sum(c^2) - (2/S) dot(c,e) ]  (wave 0) ----
    if (wid == 0) {
        float s = (lane < NW) ? swred[lane] : 0.0f;
        for (int off = 8; off > 0; off >>= 1) s += __shfl_down(s, off, 64);
        s = __shfl(s, 0, 64);                    // S on all lanes
        float v = (lane < NCLUST) ? (scsq[lane] - (2.0f / s) * sdot[lane]) : 3.0e38f;
        int bi = lane;
        for (int off = 8; off > 0; off >>= 1) {
            float ov = __shfl_down(v, off, 64);
            int   oi = __shfl_down(bi, off, 64);
            if (ov < v) { v = ov; bi = oi; }     // strict <: first-min-index
        }
        if (lane == 0) sci = bi;
    }
    __syncthreads();

    // ---- redistribute chosen center from owning wave's registers via LDS ----
    if (wid == sci) {
        float4* a4 = reinterpret_cast<float4*>(sact);
        #pragma unroll
        for (int it = 0; it < 16; ++it) a4[it * 64 + lane] = cpre[it];
    }
    // clear pass-0 histogram while waiting
    for (int k = tid; k < NW * 256; k += NT) hist[k] = 0u;
    __syncthreads();

    unsigned int cv[4];
    {
        float4 c = reinterpret_cast<const float4*>(sact)[tid];
        cv[0] = __float_as_uint(c.x);
        cv[1] = __float_as_uint(c.y);
        cv[2] = __float_as_uint(c.z);
        cv[3] = __float_as_uint(c.w);
    }

    // ---- 4-pass radix select for the 1024th-largest value ----
    for (int pass = 0; pass < 4; ++pass) {
        const int shift = 24 - 8 * pass;
        const unsigned int pfx  = sprefix;
        const unsigned int krem = sKrem;
        unsigned int* hp = &hist[wid * 256];
        #pragma unroll
        for (int j = 0; j < 4; ++j) {
            unsigned int u = cv[j];
            bool cand = (pass == 0) || ((u >> (shift + 8)) == pfx);
            if (cand) atomicAdd(&hp[(u >> shift) & 255u], 1u);
        }
        __syncthreads();
        unsigned int h = 0, s = 0;
        if (tid < 256) {
            #pragma unroll
            for (int w = 0; w < NW; ++w) h += hist[w * 256 + tid];
            s = h;  // suffix-inclusive scan within wave (bin order)
            for (int off = 1; off < 64; off <<= 1) {
                unsigned int v2 = __shfl_down(s, off, 64);
                if (lane + off < 64) s += v2;
            }
            if (lane == 0) wtot4[wid] = s;
        }
        __syncthreads();
        if (tid < 256) {
            unsigned int add = 0;
            #pragma unroll
            for (int w = 0; w < 4; ++w) if (w > wid) add += wtot4[w];
            unsigned int incl = s + add;       // # values in bins >= tid
            unsigned int excl = incl - h;      // # values in bins >  tid
            if (excl < krem && krem <= incl) { // exactly one thread matches
                sprefix = (pfx << 8) | (unsigned int)tid;
                sKrem   = krem - excl;
            }
        }
        __syncthreads();
        // clear histograms for next pass (all threads; avoids extra barrier)
        if (pass < 3) {
            for (int k = tid; k < NW * 256; k += NT) hist[k] = 0u;
            __syncthreads();
        }
    }
    const unsigned int T = sprefix;  // bit pattern of 1024th-largest value

    // ---- tie bookkeeping: G = #strictly-greater, stable eq-prefix ----
    unsigned int gt = 0, eq = 0;
    #pragma unroll
    for (int j = 0; j < 4; ++j) {
        gt += (cv[j] > T) ? 1u : 0u;
        eq += (cv[j] == T) ? 1u : 0u;
    }
    {
        unsigned int g = gt;
        for (int off = 32; off > 0; off >>= 1) g += __shfl_down(g, off, 64);
        if (lane == 0) atomicAdd(&sG, g);
    }
    unsigned int p = eq;  // inclusive prefix within wave
    for (int off = 1; off < 64; off <<= 1) {
        unsigned int v2 = __shfl_up(p, off, 64);
        if (lane >= off) p += v2;
    }
    if (lane == 63) weq[wid] = p;
    __syncthreads();
    unsigned int base = p - eq;
    #pragma unroll
    for (int w = 0; w < NW; ++w) if (w < wid) base += weq[w];
    const unsigned int needEq = TOPK - sG;

    // ---- emit masked x ----
    {
        unsigned int r = 0;
        float4 o;
        o.x = ((cv[0] > T) || ((cv[0] == T) && (base + r < needEq))) ? xv.x : 0.0f; r += (cv[0] == T);
        o.y = ((cv[1] > T) || ((cv[1] == T) && (base + r < needEq))) ? xv.y : 0.0f; r += (cv[1] == T);
        o.z = ((cv[2] > T) || ((cv[2] == T) && (base + r < needEq))) ? xv.z : 0.0f; r += (cv[2] == T);
        o.w = ((cv[3] > T) || ((cv[3] == T) && (base + r < needEq))) ? xv.w : 0.0f;
        reinterpret_cast<float4*>(xm)[tid] = o;
    }
}

// ---------------------------------------------------------------------------
// Kernel B: dense masked matvec  out[o] = W[o,:] . xm + bias[o]
// 2 rows per wave, interleaved: 32 in-flight dwordx4, shared xm LDS read.
// 1376 blocks * 4 waves * 2 rows = 11008 rows exactly.
// ---------------------------------------------------------------------------
__global__ __launch_bounds__(256) void matvec_kernel(
    const float* __restrict__ W,
    const float* __restrict__ xm,
    const float* __restrict__ bias,
    float* __restrict__ out)
{
    __shared__ __align__(16) float sxm[IN_F];
    const int tid = threadIdx.x;
    {
        const float4* src = reinterpret_cast<const float4*>(xm);
        float4* dst = reinterpret_cast<float4*>(sxm);
        #pragma unroll
        for (int i = 0; i < IN_F / 4 / 256; ++i)   // 4 iterations
            dst[i * 256 + tid] = src[i * 256 + tid];
    }
    __syncthreads();

    const int lane = tid & 63;
    const int wid  = tid >> 6;
    const int r0 = blockIdx.x * 8 + wid * 2;

    const float4* w0 = reinterpret_cast<const float4*>(W + (size_t)r0 * IN_F);
    const float4* w1 = reinterpret_cast<const float4*>(W + (size_t)(r0 + 1) * IN_F);
    const float4* x4 = reinterpret_cast<const float4*>(sxm);

    float acc0 = 0.0f, acc1 = 0.0f;
    #pragma unroll
    for (int j = 0; j < IN_F / 4 / 64; ++j) {      // 16 iterations
        float4 a = w0[j * 64 + lane];
        float4 b = w1[j * 64 + lane];
        float4 v = x4[j * 64 + lane];
        acc0 += a.x * v.x + a.y * v.y + a.z * v.z + a.w * v.w;
        acc1 += b.x * v.x + b.y * v.y + b.z * v.z + b.w * v.w;
    }
    for (int off = 32; off > 0; off >>= 1) {
        acc0 += __shfl_down(acc0, off, 64);
        acc1 += __shfl_down(acc1, off, 64);
    }
    if (lane == 0) {
        out[r0]     = acc0 + bias[r0];
        out[r0 + 1] = acc1 + bias[r0 + 1];
    }
}

extern "C" void kernel_launch(void* const* d_in, const int* in_sizes, int n_in,
                              void* d_out, int out_size, void* d_ws, size_t ws_size,
                              hipStream_t stream) {
    const float* x       = (const float*)d_in[0];  // [1,1,4096]
    const float* weight  = (const float*)d_in[1];  // [11008,4096]
    const float* bias    = (const float*)d_in[2];  // [11008]
    const float* centers = (const float*)d_in[3];  // [16,4096]
    float* out = (float*)d_out;                    // [11008]
    float* xm  = (float*)d_ws;                     // 4096 floats scratch

    select_mask_kernel<<<1, NT, 0, stream>>>(x, centers, xm);
    matvec_kernel<<<1376, 256, 0, stream>>>(weight, xm, bias, out);
}

// Round 4
// 43.695 us; speedup vs baseline: 3.4516x; 1.0391x over previous
//
#include <hip/hip_runtime.h>

#define IN_F 4096
#define OUT_F 11008
#define NCLUST 16
#define TOPK 1024
#define NBLK 256
#define ROWS_PB 43      // 256 * 43 = 11008
#define GRAN_F 1024     // floats per granule (4 KB); 4 granules per row

__device__ __forceinline__ float dot4(float4 a, float4 b) {
    return a.x * b.x + a.y * b.y + a.z * b.z + a.w * b.w;
}
__device__ __forceinline__ float wredsum(float v) {
    for (int o = 32; o > 0; o >>= 1) v += __shfl_down(v, o, 64);
    return v;
}
__device__ __forceinline__ float wredmax(float v) {
    for (int o = 32; o > 0; o >>= 1) v = fmaxf(v, __shfl_down(v, o, 64));
    return v;
}
// Raw barrier: does NOT drain vmcnt (keeps W prefetch in flight through the
// select phase). lgkmcnt(0) makes prior LDS writes visible.
__device__ __forceinline__ void barrier_lds() {
    asm volatile("s_waitcnt lgkmcnt(0)" ::: "memory");
    __builtin_amdgcn_s_barrier();
}
// Async DMA of one 4 KB granule (row quarter) into LDS. 4 x 1KB insts.
// LDS dest is wave-uniform base; HW adds lane*16. Global src is per-lane.
__device__ __forceinline__ void stage_granule(const float* __restrict__ W,
                                              int row, int q, float* lbuf,
                                              int lane) {
    const float* src = W + (size_t)row * IN_F + q * GRAN_F + lane * 4;
    #pragma unroll
    for (int j = 0; j < 4; ++j) {
        __builtin_amdgcn_global_load_lds(
            (const __attribute__((address_space(1))) void*)(src + j * 256),
            (__attribute__((address_space(3))) void*)(lbuf + j * 256),
            16, 0, 0);
    }
}

__global__ __launch_bounds__(256, 1) void fused_kernel(
    const float* __restrict__ x,
    const float* __restrict__ W,
    const float* __restrict__ bias,
    const float* __restrict__ centers,
    float* __restrict__ out)
{
    const int tid  = threadIdx.x;
    const int lane = tid & 63;
    const int wid  = tid >> 6;
    const int bid  = blockIdx.x;

    __shared__ __align__(16) float sxm[IN_F];            // e, later masked x (16 KB)
    __shared__ __align__(16) float wstage[8][GRAN_F];    // per-wave double buffers (32 KB)
    __shared__ unsigned int hist[4][256];                // wave-private histograms (4 KB)
    __shared__ float sredA[4], sredB[4];
    __shared__ float sdot[NCLUST], scsq[NCLUST];
    __shared__ unsigned int wtot4[4], weq[4];
    __shared__ unsigned int sprefix, sKrem, sG;
    __shared__ int sci;

    const int nr    = (wid < 3) ? 11 : 10;               // rows this wave (43 total)
    const int rbase = bid * ROWS_PB + wid;               // rows rbase + 4*i
    float* buf0 = &wstage[wid * 2][0];
    float* buf1 = &wstage[wid * 2 + 1][0];

    // ---- prologue: issue row0 granules 0,1 (stays in flight through select) ----
    stage_granule(W, rbase, 0, buf0, lane);
    stage_granule(W, rbase, 1, buf1, lane);
    asm volatile("" ::: "memory");

    // ================= SELECT (redundant per block) =================
    float4 x0 = ((const float4*)x)[tid * 4 + 0];
    float4 x1 = ((const float4*)x)[tid * 4 + 1];
    float4 x2 = ((const float4*)x)[tid * 4 + 2];
    float4 x3 = ((const float4*)x)[tid * 4 + 3];

    // max |x|
    {
        float m = fmaxf(fmaxf(fabsf(x0.x), fabsf(x0.y)), fmaxf(fabsf(x0.z), fabsf(x0.w)));
        m = fmaxf(m, fmaxf(fmaxf(fabsf(x1.x), fabsf(x1.y)), fmaxf(fabsf(x1.z), fabsf(x1.w))));
        m = fmaxf(m, fmaxf(fmaxf(fabsf(x2.x), fabsf(x2.y)), fmaxf(fabsf(x2.z), fabsf(x2.w))));
        m = fmaxf(m, fmaxf(fmaxf(fabsf(x3.x), fabsf(x3.y)), fmaxf(fabsf(x3.z), fabsf(x3.w))));
        m = wredmax(m);
        if (lane == 0) sredA[wid] = m;
    }
    barrier_lds();
    const float mx = fmaxf(fmaxf(sredA[0], sredA[1]), fmaxf(sredA[2], sredA[3]));

    // e = exp(|x| - mx) -> LDS, and block sum
    float e[16];
    e[0]=expf(fabsf(x0.x)-mx); e[1]=expf(fabsf(x0.y)-mx); e[2]=expf(fabsf(x0.z)-mx); e[3]=expf(fabsf(x0.w)-mx);
    e[4]=expf(fabsf(x1.x)-mx); e[5]=expf(fabsf(x1.y)-mx); e[6]=expf(fabsf(x1.z)-mx); e[7]=expf(fabsf(x1.w)-mx);
    e[8]=expf(fabsf(x2.x)-mx); e[9]=expf(fabsf(x2.y)-mx); e[10]=expf(fabsf(x2.z)-mx); e[11]=expf(fabsf(x2.w)-mx);
    e[12]=expf(fabsf(x3.x)-mx); e[13]=expf(fabsf(x3.y)-mx); e[14]=expf(fabsf(x3.z)-mx); e[15]=expf(fabsf(x3.w)-mx);
    {
        float4* sxm4 = (float4*)sxm;
        sxm4[tid*4+0] = make_float4(e[0],e[1],e[2],e[3]);
        sxm4[tid*4+1] = make_float4(e[4],e[5],e[6],e[7]);
        sxm4[tid*4+2] = make_float4(e[8],e[9],e[10],e[11]);
        sxm4[tid*4+3] = make_float4(e[12],e[13],e[14],e[15]);
        float s = 0.0f;
        #pragma unroll
        for (int k = 0; k < 16; ++k) s += e[k];
        s = wredsum(s);
        if (lane == 0) sredB[wid] = s;
    }
    barrier_lds();
    const float S = sredB[0] + sredB[1] + sredB[2] + sredB[3];

    // per-cluster dot(c,e), sum(c^2): wave w -> clusters 4w..4w+3
    {
        const float4* e4  = (const float4*)sxm;
        const float*  cb  = centers + (size_t)(4 * wid) * IN_F;
        const float4* c0p = (const float4*)(cb);
        const float4* c1p = (const float4*)(cb + IN_F);
        const float4* c2p = (const float4*)(cb + 2 * IN_F);
        const float4* c3p = (const float4*)(cb + 3 * IN_F);
        float d0=0,d1=0,d2=0,d3=0,q0=0,q1=0,q2=0,q3=0;
        #pragma unroll
        for (int j = 0; j < 16; ++j) {
            int idx = j * 64 + lane;
            float4 ev = e4[idx];
            float4 a = c0p[idx], b = c1p[idx], c = c2p[idx], d = c3p[idx];
            d0 += dot4(a, ev); q0 += dot4(a, a);
            d1 += dot4(b, ev); q1 += dot4(b, b);
            d2 += dot4(c, ev); q2 += dot4(c, c);
            d3 += dot4(d, ev); q3 += dot4(d, d);
        }
        d0 = wredsum(d0); d1 = wredsum(d1); d2 = wredsum(d2); d3 = wredsum(d3);
        q0 = wredsum(q0); q1 = wredsum(q1); q2 = wredsum(q2); q3 = wredsum(q3);
        if (lane == 0) {
            sdot[4*wid+0]=d0; sdot[4*wid+1]=d1; sdot[4*wid+2]=d2; sdot[4*wid+3]=d3;
            scsq[4*wid+0]=q0; scsq[4*wid+1]=q1; scsq[4*wid+2]=q2; scsq[4*wid+3]=q3;
        }
    }
    barrier_lds();

    // argmin_cl [ sum(c^2) - (2/S) dot(c,e) ]   (wave 0; strict < keeps first)
    if (wid == 0) {
        float v = (lane < NCLUST) ? (scsq[lane] - (2.0f / S) * sdot[lane]) : 3.0e38f;
        int bi = lane;
        for (int off = 8; off > 0; off >>= 1) {
            float ov = __shfl_down(v, off, 64);
            int   oi = __shfl_down(bi, off, 64);
            if (ov < v) { v = ov; bi = oi; }
        }
        if (lane == 0) sci = bi;
    }
    barrier_lds();
    const int ci = sci;

    // chosen center values (positive floats: uint compare == float compare)
    const float4* cc4 = (const float4*)(centers + (size_t)ci * IN_F);
    float4 c0 = cc4[tid*4+0], c1 = cc4[tid*4+1], c2 = cc4[tid*4+2], c3 = cc4[tid*4+3];
    // clear histograms + scalars while center load is in flight
    {
        unsigned int* hflat = &hist[0][0];
        hflat[tid] = 0u; hflat[tid+256] = 0u; hflat[tid+512] = 0u; hflat[tid+768] = 0u;
        if (tid == 0) { sprefix = 0u; sKrem = TOPK; sG = 0u; }
    }
    barrier_lds();

    unsigned int cv[16];
    cv[0]=__float_as_uint(c0.x); cv[1]=__float_as_uint(c0.y); cv[2]=__float_as_uint(c0.z); cv[3]=__float_as_uint(c0.w);
    cv[4]=__float_as_uint(c1.x); cv[5]=__float_as_uint(c1.y); cv[6]=__float_as_uint(c1.z); cv[7]=__float_as_uint(c1.w);
    cv[8]=__float_as_uint(c2.x); cv[9]=__float_as_uint(c2.y); cv[10]=__float_as_uint(c2.z); cv[11]=__float_as_uint(c2.w);
    cv[12]=__float_as_uint(c3.x); cv[13]=__float_as_uint(c3.y); cv[14]=__float_as_uint(c3.z); cv[15]=__float_as_uint(c3.w);

    // ---- 4-pass radix select for the 1024th-largest value ----
    for (int pass = 0; pass < 4; ++pass) {
        const int shift = 24 - 8 * pass;
        const unsigned int pfx  = sprefix;
        const unsigned int krem = sKrem;
        unsigned int* hp = hist[wid];
        #pragma unroll
        for (int k = 0; k < 16; ++k) {
            unsigned int u = cv[k];
            bool cand = (pass == 0) || ((u >> (shift + 8)) == pfx);
            if (cand) atomicAdd(&hp[(u >> shift) & 255u], 1u);
        }
        barrier_lds();
        unsigned int h, s;
        {
            const unsigned int b = tid;  // bin
            h = hist[0][b] + hist[1][b] + hist[2][b] + hist[3][b];
            hist[0][b] = 0u; hist[1][b] = 0u; hist[2][b] = 0u; hist[3][b] = 0u;  // fold clear
            s = h;  // suffix-inclusive scan (bins >= b within this wave's 64)
            for (int off = 1; off < 64; off <<= 1) {
                unsigned int v2 = __shfl_down(s, off, 64);
                if (lane + off < 64) s += v2;
            }
            if (lane == 0) wtot4[wid] = s;
        }
        barrier_lds();
        {
            unsigned int add = 0;
            #pragma unroll
            for (int w2 = 0; w2 < 4; ++w2) if (w2 > wid) add += wtot4[w2];
            unsigned int incl = s + add;       // # values in bins >= tid
            unsigned int excl = incl - h;      // # values in bins >  tid
            if (excl < krem && krem <= incl) { // exactly one thread
                sprefix = (pfx << 8) | (unsigned int)tid;
                sKrem   = krem - excl;
            }
        }
        barrier_lds();
    }
    const unsigned int T = sprefix;

    // ---- tie bookkeeping ----
    unsigned int gt = 0, eq = 0;
    #pragma unroll
    for (int k = 0; k < 16; ++k) {
        gt += (cv[k] > T) ? 1u : 0u;
        eq += (cv[k] == T) ? 1u : 0u;
    }
    {
        unsigned int g = gt;
        for (int o = 32; o > 0; o >>= 1) g += __shfl_down(g, o, 64);
        if (lane == 0) atomicAdd(&sG, g);
    }
    unsigned int p = eq;
    for (int off = 1; off < 64; off <<= 1) {
        unsigned int v2 = __shfl_up(p, off, 64);
        if (lane >= off) p += v2;
    }
    if (lane == 63) weq[wid] = p;
    barrier_lds();
    unsigned int base = p - eq;
    #pragma unroll
    for (int w2 = 0; w2 < 4; ++w2) if (w2 < wid) base += weq[w2];
    const unsigned int needEq = TOPK - sG;

    // ---- emit masked x into LDS (reuse sxm), then pull per-lane slice ----
    {
        float xs[16] = {x0.x,x0.y,x0.z,x0.w, x1.x,x1.y,x1.z,x1.w,
                        x2.x,x2.y,x2.z,x2.w, x3.x,x3.y,x3.z,x3.w};
        float os[16];
        unsigned int r = 0;
        #pragma unroll
        for (int k = 0; k < 16; ++k) {
            bool sel = (cv[k] > T) || ((cv[k] == T) && (base + r < needEq));
            os[k] = sel ? xs[k] : 0.0f;
            r += (cv[k] == T) ? 1u : 0u;
        }
        float4* sxm4 = (float4*)sxm;
        sxm4[tid*4+0] = make_float4(os[0],os[1],os[2],os[3]);
        sxm4[tid*4+1] = make_float4(os[4],os[5],os[6],os[7]);
        sxm4[tid*4+2] = make_float4(os[8],os[9],os[10],os[11]);
        sxm4[tid*4+3] = make_float4(os[12],os[13],os[14],os[15]);
    }
    barrier_lds();
    float4 slice[16];
    {
        const float4* sxm4 = (const float4*)sxm;
        #pragma unroll
        for (int k = 0; k < 16; ++k) slice[k] = sxm4[k * 64 + lane];
    }

    // ================= STREAM W (per-wave independent DMA pipeline) =========
    for (int i = 0; i < nr; ++i) {
        const int row = rbase + 4 * i;
        float acc = 0.0f;
        float bv = 0.0f;
        #pragma unroll
        for (int q = 0; q < 4; ++q) {
            const int g = i * 4 + q;
            if (g + 1 < nr * 4) { asm volatile("s_waitcnt vmcnt(4)" ::: "memory"); }
            else                { asm volatile("s_waitcnt vmcnt(0)" ::: "memory"); }
            if (q == 0) bv = bias[row];
            const float4* wb = (const float4*)((q & 1) ? buf1 : buf0);
            float4 a0 = wb[0 * 64 + lane];
            float4 a1 = wb[1 * 64 + lane];
            float4 a2 = wb[2 * 64 + lane];
            float4 a3 = wb[3 * 64 + lane];
            acc += dot4(a0, slice[q * 4 + 0]) + dot4(a1, slice[q * 4 + 1])
                 + dot4(a2, slice[q * 4 + 2]) + dot4(a3, slice[q * 4 + 3]);
            // LDS reads must retire before re-staging this buffer
            asm volatile("s_waitcnt lgkmcnt(0)" ::: "memory");
            const int g2 = g + 2;
            if (g2 < nr * 4) {
                stage_granule(W, rbase + 4 * (g2 >> 2), g2 & 3,
                              (g2 & 1) ? buf1 : buf0, lane);
            }
        }
        for (int o = 32; o > 0; o >>= 1) acc += __shfl_down(acc, o, 64);
        if (lane == 0) out[row] = acc + bv;
    }
}

extern "C" void kernel_launch(void* const* d_in, const int* in_sizes, int n_in,
                              void* d_out, int out_size, void* d_ws, size_t ws_size,
                              hipStream_t stream) {
    const float* x       = (const float*)d_in[0];  // [1,1,4096]
    const float* weight  = (const float*)d_in[1];  // [11008,4096]
    const float* bias    = (const float*)d_in[2];  // [11008]
    const float* centers = (const float*)d_in[3];  // [16,4096]
    float* out = (float*)d_out;                    // [11008]

    fused_kernel<<<NBLK, 256, 0, stream>>>(x, weight, bias, centers, out);
}